// Round 1
// baseline (119.856 us; speedup 1.0000x reference)
//
#include <hip/hip_runtime.h>
#include <stdint.h>

// Problem: out[b,e] = (x_b - c_e)^T Sigma_e^{-1} (x_b - c_e)
// E=32, B=8192, D=256, f32 in/out.
//
// Pipeline (all bf16 MFMA):
//  k_cvt    : Xbf = bf16(x); Mbf = bf16(Sigma - I); T1bf = bf16(I - M)   [= 2I - Sigma]
//  k_horner : T2 = bf16(I - M*T1) ; then Inv = bf16(I - M*T2)   (Neumann, ||M||<=0.045)
//  k_v      : v2[e][d] = 2*(Inv_e c_e)[d] (f32), s[e] = c_e . (Inv_e c_e)
//  k_main   : T = Inv_e * X^T (MFMA, f32 acc); out[b,e] = sum_n X[b,n]*(T[n,b]-v2[n]) + s[e]

#define DD   256
#define NE   32
#define NB   8192

typedef __bf16 bf16_t;
typedef bf16_t bf16x8 __attribute__((ext_vector_type(8)));
typedef bf16_t bf16x4 __attribute__((ext_vector_type(4)));
typedef float  f32x4  __attribute__((ext_vector_type(4)));

static __device__ __forceinline__ void gl2lds16(const void* g, void* l) {
  // async global->LDS, 16B per lane; LDS dest = wave-uniform base + lane*16
  __builtin_amdgcn_global_load_lds((__attribute__((address_space(1))) void*)(g),
                                   (__attribute__((address_space(3))) void*)(l),
                                   16, 0, 0);
}

// ---------------- k_cvt ----------------
// grid 2048 x 256 threads, 4 elems each: covers both NB*DD = 2M (x) and NE*DD*DD = 2M (Sigma)
__global__ __launch_bounds__(256) void k_cvt(const float* __restrict__ x,
                                             const float* __restrict__ Sg,
                                             bf16_t* __restrict__ Xbf,
                                             bf16_t* __restrict__ Mbf,
                                             bf16_t* __restrict__ T1bf) {
  int i4 = (blockIdx.x * 256 + threadIdx.x) * 4;
  // x -> bf16
  float4 xv = *(const float4*)(x + i4);
  bf16x4 xb;
  xb[0] = (bf16_t)xv.x; xb[1] = (bf16_t)xv.y; xb[2] = (bf16_t)xv.z; xb[3] = (bf16_t)xv.w;
  *(bf16x4*)(Xbf + i4) = xb;
  // Sigma -> M = S - I (bf16), T1 = I - M (bf16)
  float4 sv = *(const float4*)(Sg + i4);
  int r  = (i4 >> 8) & 255;
  int c0 = i4 & 255;
  bf16x4 mo, to;
  float sarr[4] = {sv.x, sv.y, sv.z, sv.w};
#pragma unroll
  for (int t = 0; t < 4; ++t) {
    float dg = (r == (c0 + t)) ? 1.0f : 0.0f;
    float m  = sarr[t] - dg;
    mo[t] = (bf16_t)m;
    to[t] = (bf16_t)(dg - m);
  }
  *(bf16x4*)(Mbf + i4)  = mo;
  *(bf16x4*)(T1bf + i4) = to;
}

// ---------------- k_horner ----------------
// C = bf16(I - M*T), per e. grid (4, NE): blockIdx.x = 64-col tile, blockIdx.y = e.
// T symmetric (polynomial in symmetric M) -> B-operand B[k][c] = T[c][k] read as rows.
__global__ __launch_bounds__(512, 2) void k_horner(const bf16_t* __restrict__ Mg,
                                                   const bf16_t* __restrict__ Tg,
                                                   bf16_t* __restrict__ Cg) {
  int ct = blockIdx.x;
  int e  = blockIdx.y;
  int tid = threadIdx.x, w = tid >> 6, l = tid & 63;
  __shared__ bf16_t Ml[256 * 32];  // 16KB: M[n][k-chunk]
  __shared__ bf16_t Tl[64 * 32];   //  4KB: T[c][k-chunk]
  const bf16_t* Me = Mg + e * 65536;
  const bf16_t* Te = Tg + e * 65536 + (ct * 64) * 256;

  f32x4 acc[2][4];
#pragma unroll
  for (int a = 0; a < 2; ++a)
#pragma unroll
    for (int b = 0; b < 4; ++b) acc[a][b] = (f32x4){0.f, 0.f, 0.f, 0.f};

  int arow0 = w * 32 + (l & 15);
  int acol  = (l >> 4) * 8;

  for (int kk = 0; kk < 256; kk += 32) {
    for (int i = w; i < 16; i += 8)
      gl2lds16(Me + (i * 16 + (l >> 2)) * 256 + kk + (l & 3) * 8, Ml + i * 512);
    for (int i = w; i < 4; i += 8)
      gl2lds16(Te + (i * 16 + (l >> 2)) * 256 + kk + (l & 3) * 8, Tl + i * 512);
    __syncthreads();
    bf16x8 a0 = *(const bf16x8*)&Ml[arow0 * 32 + acol];
    bf16x8 a1 = *(const bf16x8*)&Ml[(arow0 + 16) * 32 + acol];
#pragma unroll
    for (int bf = 0; bf < 4; ++bf) {
      bf16x8 bb = *(const bf16x8*)&Tl[(bf * 16 + (l & 15)) * 32 + acol];
      acc[0][bf] = __builtin_amdgcn_mfma_f32_16x16x32_bf16(a0, bb, acc[0][bf], 0, 0, 0);
      acc[1][bf] = __builtin_amdgcn_mfma_f32_16x16x32_bf16(a1, bb, acc[1][bf], 0, 0, 0);
    }
    __syncthreads();
  }
  // C[n][c] = bf16(diag - acc); D-frag: col = l&15, row = (l>>4)*4 + q
  int c0 = ct * 64;
#pragma unroll
  for (int nf = 0; nf < 2; ++nf) {
    int nb = w * 32 + nf * 16 + (l >> 4) * 4;
#pragma unroll
    for (int bf = 0; bf < 4; ++bf) {
      int c = c0 + bf * 16 + (l & 15);
#pragma unroll
      for (int q = 0; q < 4; ++q) {
        int n = nb + q;
        float vv = ((n == c) ? 1.0f : 0.0f) - acc[nf][bf][q];
        Cg[e * 65536 + n * 256 + c] = (bf16_t)vv;
      }
    }
  }
}

// ---------------- k_v ----------------
// v2[e][d] = 2 * sum_k Inv[k][d]*c[k] (symmetry -> coalesced), s[e] = sum_d c[d]*v[d]
__global__ __launch_bounds__(256) void k_v(const bf16_t* __restrict__ Invbf,
                                           const float* __restrict__ Cent,
                                           float* __restrict__ v2,
                                           float* __restrict__ s_out) {
  int e = blockIdx.x, d = threadIdx.x;
  __shared__ float cl[256];
  __shared__ float ps[256];
  cl[d] = Cent[e * 256 + d];
  __syncthreads();
  const bf16_t* Ie = Invbf + e * 65536;
  float acc = 0.f;
  for (int k = 0; k < 256; ++k) acc += (float)Ie[k * 256 + d] * cl[k];
  v2[e * 256 + d] = 2.0f * acc;
  ps[d] = cl[d] * acc;
  __syncthreads();
  for (int off = 128; off > 0; off >>= 1) {
    if (d < off) ps[d] += ps[d + off];
    __syncthreads();
  }
  if (d == 0) s_out[e] = ps[0];
}

// ---------------- k_main ----------------
// grid (32 b-tiles, NE e). 512 threads = 8 waves (2 n-groups x 4 b-groups).
// X tile [256][256] bf16 resident in LDS (B-operand + epilogue); Inv streamed in [256][32] chunks.
__global__ __launch_bounds__(512, 2) void k_main(const bf16_t* __restrict__ Xbf,
                                                 const bf16_t* __restrict__ Invbf,
                                                 const float* __restrict__ v2,
                                                 const float* __restrict__ s_in,
                                                 float* __restrict__ out) {
  int bt = blockIdx.x;
  int e  = blockIdx.y;
  int tid = threadIdx.x, w = tid >> 6, l = tid & 63;
  __shared__ bf16_t Xl[256 * 256];   // 128KB
  __shared__ bf16_t Invl[256 * 32];  // 16KB
  __shared__ float  v2l[256];        // 1KB
  __shared__ float  red[2][256];     // 2KB

  const bf16_t* Xg = Xbf + bt * 256 * 256;
  // stage X tile: 128 insts x 1KB (2 rows each)
  for (int i = w; i < 128; i += 8) {
    const bf16_t* g = Xg + (i * 2 + (l >> 5)) * 256 + (l & 31) * 8;
    gl2lds16(g, Xl + i * 512);
  }
  if (w == 0) gl2lds16(v2 + e * 256 + l * 4, v2l);

  f32x4 acc[8][4];
#pragma unroll
  for (int a = 0; a < 8; ++a)
#pragma unroll
    for (int b = 0; b < 4; ++b) acc[a][b] = (f32x4){0.f, 0.f, 0.f, 0.f};

  int wn = w >> 2, wb = w & 3;
  int arow = wn * 128 + (l & 15);
  int acol = (l >> 4) * 8;
  int brow = wb * 64 + (l & 15);
  const bf16_t* Ig = Invbf + e * 65536;

  for (int kk = 0; kk < 256; kk += 32) {
    for (int i = w; i < 16; i += 8)
      gl2lds16(Ig + (i * 16 + (l >> 2)) * 256 + kk + (l & 3) * 8, Invl + i * 512);
    __syncthreads();  // drains vmcnt (incl. X staging on first iter)
    bf16x8 af[8];
#pragma unroll
    for (int nf = 0; nf < 8; ++nf)
      af[nf] = *(const bf16x8*)&Invl[(arow + nf * 16) * 32 + acol];
    bf16x8 bfr[4];
#pragma unroll
    for (int bf = 0; bf < 4; ++bf)
      bfr[bf] = *(const bf16x8*)&Xl[(brow + bf * 16) * 256 + kk + acol];
#pragma unroll
    for (int nf = 0; nf < 8; ++nf)
#pragma unroll
      for (int bf = 0; bf < 4; ++bf)
        acc[nf][bf] = __builtin_amdgcn_mfma_f32_16x16x32_bf16(af[nf], bfr[bf], acc[nf][bf], 0, 0, 0);
    __syncthreads();
  }

  // epilogue: bsum[b] = sum_n X[b,n]*(T[n,b]-v2[n]); lane's 4 regs are consecutive n
  float bsum[4] = {0.f, 0.f, 0.f, 0.f};
#pragma unroll
  for (int nf = 0; nf < 8; ++nf) {
    int nb = wn * 128 + nf * 16 + (l >> 4) * 4;
    f32x4 vv = *(const f32x4*)&v2l[nb];
#pragma unroll
    for (int bf = 0; bf < 4; ++bf) {
      int b = wb * 64 + bf * 16 + (l & 15);
      const bf16_t* xp = &Xl[b * 256 + nb];
      f32x4 a = acc[nf][bf];
      bsum[bf] += (float)xp[0] * (a[0] - vv[0]) + (float)xp[1] * (a[1] - vv[1]) +
                  (float)xp[2] * (a[2] - vv[2]) + (float)xp[3] * (a[3] - vv[3]);
    }
  }
#pragma unroll
  for (int bf = 0; bf < 4; ++bf) {
    float r = bsum[bf];
    r += __shfl_xor(r, 16);
    r += __shfl_xor(r, 32);
    if ((l >> 4) == 0) red[wn][wb * 64 + bf * 16 + l] = r;
  }
  __syncthreads();
  if (tid < 256) {
    int b = tid;
    float res = s_in[e] + red[0][b] + red[1][b];
    out[(bt * 256 + b) * 32 + e] = res;
  }
}

extern "C" void kernel_launch(void* const* d_in, const int* in_sizes, int n_in,
                              void* d_out, int out_size, void* d_ws, size_t ws_size,
                              hipStream_t stream) {
  const float* x    = (const float*)d_in[0];
  const float* cent = (const float*)d_in[1];
  const float* sig  = (const float*)d_in[2];
  float* out = (float*)d_out;

  char* ws = (char*)d_ws;
  bf16_t* Xbf   = (bf16_t*)(ws);
  bf16_t* Mbf   = (bf16_t*)(ws + (4ull << 20));
  bf16_t* T1bf  = (bf16_t*)(ws + (8ull << 20));
  bf16_t* T2bf  = (bf16_t*)(ws + (12ull << 20));
  bf16_t* Invbf = T1bf;  // horner #2 overwrites T1 slot (reads M, T2 only)
  float*  v2    = (float*)(ws + (16ull << 20));
  float*  sArr  = (float*)(ws + (16ull << 20) + 32768);

  k_cvt<<<dim3(2048), dim3(256), 0, stream>>>(x, sig, Xbf, Mbf, T1bf);
  k_horner<<<dim3(4, NE), dim3(512), 0, stream>>>(Mbf, T1bf, T2bf);
  k_horner<<<dim3(4, NE), dim3(512), 0, stream>>>(Mbf, T2bf, Invbf);
  k_v<<<dim3(NE), dim3(256), 0, stream>>>(Invbf, cent, v2, sArr);
  k_main<<<dim3(32, NE), dim3(512), 0, stream>>>(Xbf, Invbf, v2, sArr, out);
}

// Round 2
// 71.475 us; speedup vs baseline: 1.6769x; 1.6769x over previous
//
#include <hip/hip_runtime.h>
#include <stdint.h>

// out[b,e] = (x_b - c_e)^T Sigma_e^{-1} (x_b - c_e);  E=32, B=8192, D=256, f32.
// Pipeline:
//  k_x   : Xbf = bf16(x)
//  k_inv : per (e, 32-col chunk): M = bf16(Sigma - I) staged in padded LDS;
//          V = M*M (MFMA, sym B); T2 = I - M + V (transposed LDS store);
//          Inv = I - M*T2  ->  I - M + M^2 - M^3  (Neumann, ||M||~0.045)
//  k_v   : v2[e] = 2*Inv_e c_e (row-major via symmetry), s[e] = c^T Inv c
//  k_main: grid(32 bt, 8 eg), e-loop of 4. X tile resident (padded LDS, staged once);
//          Inv streamed in 16KB K-chunks via T14 reg-staging (issue-early/write-late).
//          acc = Inv * X^T; out[b,e] = sum_n X[b,n]*(acc[n,b]-v2[n]) + s[e]

#define NE 32
#define NB 8192
#define DD 256

typedef __bf16 bf16_t;
typedef bf16_t bf16x8 __attribute__((ext_vector_type(8)));
typedef bf16_t bf16x4 __attribute__((ext_vector_type(4)));
typedef float  f32x4  __attribute__((ext_vector_type(4)));

#define LDX 264  // X / M tile row stride in elems (528B: bank-spread, 16B-aligned)
#define LDI 40   // Inv K-chunk row stride (80B: bank base advances 20 -> full spread)
#define LDT 264  // T2t row stride

// ---------------- k_x : f32 -> bf16 ----------------
__global__ __launch_bounds__(256) void k_x(const float* __restrict__ x,
                                           bf16_t* __restrict__ Xbf) {
  int i8 = (blockIdx.x * 256 + threadIdx.x) * 8;
  f32x4 a = *(const f32x4*)(x + i8);
  f32x4 b = *(const f32x4*)(x + i8 + 4);
  bf16x8 o;
  o[0] = (bf16_t)a[0]; o[1] = (bf16_t)a[1]; o[2] = (bf16_t)a[2]; o[3] = (bf16_t)a[3];
  o[4] = (bf16_t)b[0]; o[5] = (bf16_t)b[1]; o[6] = (bf16_t)b[2]; o[7] = (bf16_t)b[3];
  *(bf16x8*)(Xbf + i8) = o;
}

// ---------------- k_inv : fused Neumann inverse ----------------
// grid (8 col-chunks, NE e), 512 threads = 8 waves (each owns 32 A-rows).
__global__ __launch_bounds__(512, 2) void k_inv(const float* __restrict__ Sg,
                                                bf16_t* __restrict__ Invbf) {
  int ct = blockIdx.x;
  int e  = blockIdx.y;
  int tid = threadIdx.x, w = tid >> 6, l = tid & 63;
  __shared__ bf16_t Ml[256 * LDX];   // 132KB padded M
  __shared__ bf16_t T2t[32 * LDT];   // 16.5KB  T2t[c][n] = T2[n][cg]
  const float* Se = Sg + (size_t)e * 65536;

  // stage M = Sigma - I (f32->bf16), padded rows
#pragma unroll
  for (int i = 0; i < 16; ++i) {
    int s = i * 512 + tid;
    int row = s >> 5, c8 = (s & 31) * 8;
    f32x4 a = *(const f32x4*)(Se + row * 256 + c8);
    f32x4 b = *(const f32x4*)(Se + row * 256 + c8 + 4);
    float v[8] = {a[0], a[1], a[2], a[3], b[0], b[1], b[2], b[3]};
    int dj = row - c8;
    if (dj >= 0 && dj < 8) v[dj] -= 1.0f;
    bf16x8 o;
#pragma unroll
    for (int j = 0; j < 8; ++j) o[j] = (bf16_t)v[j];
    *(bf16x8*)&Ml[row * LDX + c8] = o;
  }
  __syncthreads();

  int rA = w * 32 + (l & 15);   // A-row base (this wave)
  int q8 = (l >> 4) * 8;        // k-offset within K=32 fragment
  int cg0 = ct * 32;

  // GEMM1: V = M*M   (B-frag via symmetry: M[k][cg] = M[cg][k], row-major read)
  f32x4 acc1[2][2];
#pragma unroll
  for (int i = 0; i < 2; ++i)
#pragma unroll
    for (int j = 0; j < 2; ++j) acc1[i][j] = (f32x4){0.f, 0.f, 0.f, 0.f};
#pragma unroll
  for (int kk = 0; kk < 256; kk += 32) {
    bf16x8 a0 = *(const bf16x8*)&Ml[rA * LDX + kk + q8];
    bf16x8 a1 = *(const bf16x8*)&Ml[(rA + 16) * LDX + kk + q8];
    bf16x8 b0 = *(const bf16x8*)&Ml[(cg0 + (l & 15)) * LDX + kk + q8];
    bf16x8 b1 = *(const bf16x8*)&Ml[(cg0 + 16 + (l & 15)) * LDX + kk + q8];
    acc1[0][0] = __builtin_amdgcn_mfma_f32_16x16x32_bf16(a0, b0, acc1[0][0], 0, 0, 0);
    acc1[0][1] = __builtin_amdgcn_mfma_f32_16x16x32_bf16(a0, b1, acc1[0][1], 0, 0, 0);
    acc1[1][0] = __builtin_amdgcn_mfma_f32_16x16x32_bf16(a1, b0, acc1[1][0], 0, 0, 0);
    acc1[1][1] = __builtin_amdgcn_mfma_f32_16x16x32_bf16(a1, b1, acc1[1][1], 0, 0, 0);
  }
  // T2t[c][n] = T2[n][cg] = delta - M[n][cg] + V[n][cg]; M[n][cg] read as M[cg][n] (sym)
#pragma unroll
  for (int nf = 0; nf < 2; ++nf) {
    int n0 = w * 32 + nf * 16 + (l >> 4) * 4;
#pragma unroll
    for (int cf = 0; cf < 2; ++cf) {
      int cl = cf * 16 + (l & 15), cg = cg0 + cl;
      bf16x4 mr = *(const bf16x4*)&Ml[cg * LDX + n0];
      f32x4 vv = acc1[nf][cf];
      bf16x4 o;
#pragma unroll
      for (int q = 0; q < 4; ++q) {
        float t2 = (((n0 + q) == cg) ? 1.0f : 0.0f) - (float)mr[q] + vv[q];
        o[q] = (bf16_t)t2;
      }
      *(bf16x4*)&T2t[cl * LDT + n0] = o;
    }
  }
  __syncthreads();

  // GEMM2: acc2 = M * T2
  f32x4 acc2[2][2];
#pragma unroll
  for (int i = 0; i < 2; ++i)
#pragma unroll
    for (int j = 0; j < 2; ++j) acc2[i][j] = (f32x4){0.f, 0.f, 0.f, 0.f};
#pragma unroll
  for (int kk = 0; kk < 256; kk += 32) {
    bf16x8 a0 = *(const bf16x8*)&Ml[rA * LDX + kk + q8];
    bf16x8 a1 = *(const bf16x8*)&Ml[(rA + 16) * LDX + kk + q8];
    bf16x8 b0 = *(const bf16x8*)&T2t[(l & 15) * LDT + kk + q8];
    bf16x8 b1 = *(const bf16x8*)&T2t[(16 + (l & 15)) * LDT + kk + q8];
    acc2[0][0] = __builtin_amdgcn_mfma_f32_16x16x32_bf16(a0, b0, acc2[0][0], 0, 0, 0);
    acc2[0][1] = __builtin_amdgcn_mfma_f32_16x16x32_bf16(a0, b1, acc2[0][1], 0, 0, 0);
    acc2[1][0] = __builtin_amdgcn_mfma_f32_16x16x32_bf16(a1, b0, acc2[1][0], 0, 0, 0);
    acc2[1][1] = __builtin_amdgcn_mfma_f32_16x16x32_bf16(a1, b1, acc2[1][1], 0, 0, 0);
  }
  // Inv[n][cg] = delta - acc2
  bf16_t* Ce = Invbf + (size_t)e * 65536;
#pragma unroll
  for (int nf = 0; nf < 2; ++nf) {
    int n0 = w * 32 + nf * 16 + (l >> 4) * 4;
#pragma unroll
    for (int cf = 0; cf < 2; ++cf) {
      int cg = cg0 + cf * 16 + (l & 15);
#pragma unroll
      for (int q = 0; q < 4; ++q) {
        float vv = (((n0 + q) == cg) ? 1.0f : 0.0f) - acc2[nf][cf][q];
        Ce[(n0 + q) * 256 + cg] = (bf16_t)vv;
      }
    }
  }
}

// ---------------- k_v : v2 = 2*Inv*c, s = c^T Inv c ----------------
__global__ __launch_bounds__(256) void k_v(const bf16_t* __restrict__ Invbf,
                                           const float* __restrict__ Cent,
                                           float* __restrict__ v2,
                                           float* __restrict__ s_out) {
  int e = blockIdx.x, d = threadIdx.x;
  __shared__ float cl[256];
  __shared__ float ps[256];
  cl[d] = Cent[e * 256 + d];
  __syncthreads();
  const bf16_t* Ie = Invbf + (size_t)e * 65536 + d * 256;  // row d (symmetry)
  float acc = 0.f;
#pragma unroll
  for (int k8 = 0; k8 < 256; k8 += 8) {
    bf16x8 r = *(const bf16x8*)(Ie + k8);
#pragma unroll
    for (int j = 0; j < 8; ++j) acc += (float)r[j] * cl[k8 + j];
  }
  v2[e * 256 + d] = 2.0f * acc;
  ps[d] = cl[d] * acc;
  __syncthreads();
  for (int off = 128; off > 0; off >>= 1) {
    if (d < off) ps[d] += ps[d + off];
    __syncthreads();
  }
  if (d == 0) s_out[e] = ps[0];
}

// ---------------- k_main ----------------
// grid (32 bt, 8 eg), 512 thr = 8 waves (2 n-groups x 4 b-groups), e-loop of 4.
__global__ __launch_bounds__(512, 2) void k_main(const bf16_t* __restrict__ Xbf,
                                                 const bf16_t* __restrict__ Invbf,
                                                 const float* __restrict__ v2g,
                                                 const float* __restrict__ sg,
                                                 float* __restrict__ out) {
  int bt = blockIdx.x;
  int eg = blockIdx.y;
  int tid = threadIdx.x, w = tid >> 6, l = tid & 63;
  __shared__ bf16_t Xl[256 * LDX];    // 132KB padded X tile
  __shared__ bf16_t Invl[256 * LDI];  // 20KB padded Inv K-chunk (red aliases this)
  const bf16_t* Xg = Xbf + (size_t)bt * 65536;

  // one-time X stage: reg-staged, padded rows (2 rounds of 8 x 16B per thread)
#pragma unroll
  for (int r = 0; r < 2; ++r) {
    f32x4 tmp[8];
#pragma unroll
    for (int i = 0; i < 8; ++i) {
      int s = (r * 8 + i) * 512 + tid;
      int row = s >> 5, sl = s & 31;
      tmp[i] = *(const f32x4*)(Xg + row * 256 + sl * 8);
    }
#pragma unroll
    for (int i = 0; i < 8; ++i) {
      int s = (r * 8 + i) * 512 + tid;
      int row = s >> 5, sl = s & 31;
      *(f32x4*)&Xl[row * LDX + sl * 8] = tmp[i];
    }
  }

  int wn = w >> 2, wb = w & 3;
  int arow = wn * 128 + (l & 15);
  int q8 = (l >> 4) * 8;
  int brow = wb * 64 + (l & 15);
  int srow0 = tid >> 2, ssl0 = (tid & 3) * 8;          // chunk slot 0 (rows 0..127)
  int srow1 = (tid + 512) >> 2, ssl1 = ssl0;           // chunk slot 1 (rows 128..255)
  float* redp = (float*)Invl;                          // 2KB alias, used in epilogue

  for (int ei = 0; ei < 4; ++ei) {
    int e = eg * 4 + ei;
    const bf16_t* Ig = Invbf + (size_t)e * 65536;

    // prologue: chunk 0 (issue loads, barrier vs prior epilogue/X-stage, write)
    f32x4 cA = *(const f32x4*)(Ig + srow0 * 256 + ssl0);
    f32x4 cB = *(const f32x4*)(Ig + srow1 * 256 + ssl1);
    __syncthreads();
    *(f32x4*)&Invl[srow0 * LDI + ssl0] = cA;
    *(f32x4*)&Invl[srow1 * LDI + ssl1] = cB;
    __syncthreads();

    f32x4 acc[8][4];
#pragma unroll
    for (int a = 0; a < 8; ++a)
#pragma unroll
      for (int b = 0; b < 4; ++b) acc[a][b] = (f32x4){0.f, 0.f, 0.f, 0.f};

#pragma unroll
    for (int t = 0; t < 8; ++t) {
      int kk = t * 32;
      if (t < 7) {  // T14: issue next-chunk loads early
        cA = *(const f32x4*)(Ig + srow0 * 256 + kk + 32 + ssl0);
        cB = *(const f32x4*)(Ig + srow1 * 256 + kk + 32 + ssl1);
      }
      bf16x8 af[8];
#pragma unroll
      for (int nf = 0; nf < 8; ++nf)
        af[nf] = *(const bf16x8*)&Invl[(arow + nf * 16) * LDI + q8];
      bf16x8 bfr[4];
#pragma unroll
      for (int bf = 0; bf < 4; ++bf)
        bfr[bf] = *(const bf16x8*)&Xl[(brow + bf * 16) * LDX + kk + q8];
#pragma unroll
      for (int nf = 0; nf < 8; ++nf)
#pragma unroll
        for (int bf = 0; bf < 4; ++bf)
          acc[nf][bf] = __builtin_amdgcn_mfma_f32_16x16x32_bf16(af[nf], bfr[bf], acc[nf][bf], 0, 0, 0);
      __syncthreads();  // all waves done reading Invl chunk t
      if (t < 7) {      // write-late (vmcnt drained at barrier above)
        *(f32x4*)&Invl[srow0 * LDI + ssl0] = cA;
        *(f32x4*)&Invl[srow1 * LDI + ssl1] = cB;
        __syncthreads();
      }
    }

    // epilogue: bsum[b] = sum_n X[b,n]*(acc[n,b]-v2[n])
    float bsum[4] = {0.f, 0.f, 0.f, 0.f};
#pragma unroll
    for (int nf = 0; nf < 8; ++nf) {
      int nb = wn * 128 + nf * 16 + (l >> 4) * 4;
      f32x4 vv = *(const f32x4*)(v2g + e * 256 + nb);
#pragma unroll
      for (int bf = 0; bf < 4; ++bf) {
        int b = wb * 64 + bf * 16 + (l & 15);
        bf16x4 xr = *(const bf16x4*)&Xl[b * LDX + nb];
        f32x4 a = acc[nf][bf];
        bsum[bf] += (float)xr[0] * (a[0] - vv[0]) + (float)xr[1] * (a[1] - vv[1]) +
                    (float)xr[2] * (a[2] - vv[2]) + (float)xr[3] * (a[3] - vv[3]);
      }
    }
#pragma unroll
    for (int bf = 0; bf < 4; ++bf) {
      float r = bsum[bf];
      r += __shfl_xor(r, 16);
      r += __shfl_xor(r, 32);
      if ((l >> 4) == 0) redp[wn * 256 + wb * 64 + bf * 16 + l] = r;
    }
    __syncthreads();
    if (tid < 256) {
      float res = sg[e] + redp[tid] + redp[256 + tid];
      out[(size_t)(bt * 256 + tid) * 32 + e] = res;
    }
    // next-iteration prologue barrier protects redp (=Invl) before overwrite
  }
}

extern "C" void kernel_launch(void* const* d_in, const int* in_sizes, int n_in,
                              void* d_out, int out_size, void* d_ws, size_t ws_size,
                              hipStream_t stream) {
  const float* x    = (const float*)d_in[0];
  const float* cent = (const float*)d_in[1];
  const float* sig  = (const float*)d_in[2];
  float* out = (float*)d_out;

  char* ws = (char*)d_ws;
  bf16_t* Xbf   = (bf16_t*)(ws);                      // 4MB
  bf16_t* Invbf = (bf16_t*)(ws + (4ull << 20));       // 4MB
  float*  v2    = (float*)(ws + (8ull << 20));        // 32KB
  float*  sArr  = (float*)(ws + (8ull << 20) + 32768);

  k_x  <<<dim3(1024),      dim3(256), 0, stream>>>(x, Xbf);
  k_inv<<<dim3(8, NE),     dim3(512), 0, stream>>>(sig, Invbf);
  k_v  <<<dim3(NE),        dim3(256), 0, stream>>>(Invbf, cent, v2, sArr);
  k_main<<<dim3(32, 8),    dim3(512), 0, stream>>>(Xbf, Invbf, v2, sArr, out);
}